// Round 1
// 467.035 us; speedup vs baseline: 1.0439x; 1.0439x over previous
//
#include <hip/hip_runtime.h>
#include <stdint.h>

#define D_MODEL 2048
#define N_EXP   64
#define TOKS    32                  // tokens per block
#define WAVES   4                   // 256 threads
#define KW      (D_MODEL / WAVES)   // 512 k per wave (private K-split)
#define KSS     32                  // k per stage (halved; double-buffered)
#define NSS     (KW / KSS)          // 16 stages
#define ROW_F4  8                   // 32 k = 8 float4 per token row (NO pad; XOR swizzle)
#define BUF_F4  (TOKS * ROW_F4)     // 256 float4 per wave-buffer (4 KB)

// ---- W repack: Wq2[kq][j][eg] = float4{ W[8j+eg][4kq+i] }, 512 KB in d_ws --
__global__ void make_Wq2(const float* __restrict__ W, float* __restrict__ Wq2) {
    int o  = blockIdx.x * 256 + threadIdx.x;
    int i  = o & 3;
    int eg = (o >> 2) & 7;
    int j  = (o >> 5) & 7;
    int kq = o >> 8;
    Wq2[o] = W[(8 * j + eg) * D_MODEL + 4 * kq + i];
}

union SMemU {
    float4 xs[2 * WAVES * BUF_F4];      // 32768 B: double-buffered per-wave staging
    float  red[2][TOKS * 65];           // 16640 B reduction overlay (pad 65)
};

__global__ __launch_bounds__(256, 4)
void router_d(const float* __restrict__ x, const float4* __restrict__ Wq2,
              const float* __restrict__ bias, float* __restrict__ out, int n_tokens)
{
    __shared__ SMemU sm;
    const int tid  = threadIdx.x;
    const int lane = tid & 63;
    const int wv   = tid >> 6;
    const int tg   = lane >> 3;       // token group: tokens t = 8*tt + tg
    const int eg   = lane & 7;        // expert group: experts e = 8*j + eg
    const int tok0 = blockIdx.x * TOKS;
    const int kw   = wv * KW;

    // staging lane decomposition: each instr covers 8 tokens x 8 float4 (128B/token)
    const int trow = lane >> 3;       // 0..7  (== t & 7 for t = 8*it + trow)
    const int c    = lane & 7;        // 0..7
    const int gc   = c ^ trow;        // pre-swizzled GLOBAL column; LDS stays linear

    float acc[4][8];
    #pragma unroll
    for (int tt = 0; tt < 4; ++tt)
        #pragma unroll
        for (int j = 0; j < 8; ++j) acc[tt][j] = 0.f;

    // per-wave private double buffers: no barriers in main loop
    float4* b0 = sm.xs + (0 * WAVES + wv) * BUF_F4;
    float4* b1 = sm.xs + (1 * WAVES + wv) * BUF_F4;

    auto stage = [&](int s, float4* lb) {
        const int kb = kw + s * KSS;
        #pragma unroll
        for (int it = 0; it < 4; ++it) {
            const int t = 8 * it + trow;
            const float* gp = x + (size_t)(tok0 + t) * D_MODEL + kb + 4 * gc;
            __builtin_amdgcn_global_load_lds(
                (const __attribute__((address_space(1))) void*)gp,
                (__attribute__((address_space(3))) void*)(lb + it * 64), 16, 0, 0);
        }
    };

    stage(0, b0);                         // prologue: fill pipe

    for (int s = 0; s < NSS; ++s) {
        float4* cb = (s & 1) ? b1 : b0;   // compute buffer for stage s
        if (s + 1 < NSS) {
            stage(s + 1, (s & 1) ? b0 : b1);
            // keep the newest 4 (stage s+1) in flight; drain stage s + stale W loads
            asm volatile("s_waitcnt vmcnt(4)" ::: "memory");
        } else {
            asm volatile("s_waitcnt vmcnt(0)" ::: "memory");
        }
        const int kb = kw + s * KSS;
        // ---- compute: 8 kq x (4 ds_read_b128 + 8 W float4 + 128 FMA) --------
        #pragma unroll
        for (int q = 0; q < KSS / 4; ++q) {
            const int kq = (kb >> 2) + q;
            float4 xv[4];
            #pragma unroll
            for (int tt = 0; tt < 4; ++tt) {
                const int t = 8 * tt + tg;
                xv[tt] = cb[(size_t)t * ROW_F4 + (q ^ tg)];  // conflict-free quads
            }
            const float4* wp = Wq2 + (size_t)kq * 64 + eg;
            #pragma unroll
            for (int j = 0; j < 8; ++j) {
                const float4 w4 = wp[8 * j];                 // 128B coalesced, L2-hit
                #pragma unroll
                for (int tt = 0; tt < 4; ++tt) {
                    acc[tt][j] = fmaf(w4.x, xv[tt].x, acc[tt][j]);
                    acc[tt][j] = fmaf(w4.y, xv[tt].y, acc[tt][j]);
                    acc[tt][j] = fmaf(w4.z, xv[tt].z, acc[tt][j]);
                    acc[tt][j] = fmaf(w4.w, xv[tt].w, acc[tt][j]);
                }
            }
        }
    }

    // ---- cross-wave reduction: 4 K-partials -> wave 0 -----------------------
    __syncthreads();                      // staging dead; overlay becomes live
    if (wv >= 2) {
        float* R = sm.red[wv - 2];
        #pragma unroll
        for (int tt = 0; tt < 4; ++tt)
            #pragma unroll
            for (int j = 0; j < 8; ++j)
                R[(8 * tt + tg) * 65 + 8 * j + eg] = acc[tt][j];
    }
    __syncthreads();
    if (wv < 2) {
        const float* R = sm.red[wv];
        #pragma unroll
        for (int tt = 0; tt < 4; ++tt)
            #pragma unroll
            for (int j = 0; j < 8; ++j)
                acc[tt][j] += R[(8 * tt + tg) * 65 + 8 * j + eg];
    }
    __syncthreads();
    if (wv == 1) {
        float* R = sm.red[0];
        #pragma unroll
        for (int tt = 0; tt < 4; ++tt)
            #pragma unroll
            for (int j = 0; j < 8; ++j)
                R[(8 * tt + tg) * 65 + 8 * j + eg] = acc[tt][j];
    }
    __syncthreads();

    // ---- epilogue: bias + top-2 + softmax, wave 0 ---------------------------
    if (wv == 0) {
        const float* R = sm.red[0];
        float bj[8];
        #pragma unroll
        for (int j = 0; j < 8; ++j) bj[j] = bias[8 * j + eg];
        float* ow = out + 2 * (size_t)n_tokens;

        #pragma unroll
        for (int tt = 0; tt < 4; ++tt) {
            float v[8];
            #pragma unroll
            for (int j = 0; j < 8; ++j)
                v[j] = acc[tt][j] + R[(8 * tt + tg) * 65 + 8 * j + eg] + bj[j];
            // local top-2 over this lane's 8 experts (e = 8j+eg ascending)
            float v1 = v[0]; int i1 = eg;
            float v2 = -3.4e38f; int i2 = 1 << 20;
            #pragma unroll
            for (int j = 1; j < 8; ++j) {
                const int e = 8 * j + eg;
                if (v[j] > v1)      { v2 = v1; i2 = i1; v1 = v[j]; i1 = e; }
                else if (v[j] > v2) { v2 = v[j]; i2 = e; }
            }
            // butterfly merge across the 8 eg-lanes (tie: lower index)
            #pragma unroll
            for (int m = 1; m < 8; m <<= 1) {
                float b1 = __shfl_xor(v1, m, 64); int j1 = __shfl_xor(i1, m, 64);
                float b2 = __shfl_xor(v2, m, 64); int j2 = __shfl_xor(i2, m, 64);
                bool aw = (v1 > b1) || (v1 == b1 && i1 < j1);
                float lw_v = aw ? b1 : v1;  int lw_i = aw ? j1 : i1;
                float ws_v = aw ? v2 : b2;  int ws_i = aw ? i2 : j2;
                float nv1  = aw ? v1 : b1;  int ni1  = aw ? i1 : j1;
                bool sw = (lw_v > ws_v) || (lw_v == ws_v && lw_i < ws_i);
                v1 = nv1;               i1 = ni1;
                v2 = sw ? lw_v : ws_v;  i2 = sw ? lw_i : ws_i;
            }
            // softmax denominator over all 64 experts
            float ssum = 0.f;
            #pragma unroll
            for (int j = 0; j < 8; ++j) ssum += __expf(v[j] - v1);
            #pragma unroll
            for (int m = 1; m < 8; m <<= 1) ssum += __shfl_xor(ssum, m, 64);
            const float inv = 1.0f / ssum;
            const float w1  = inv;
            const float w2  = __expf(v2 - v1) * inv;

            if (eg == tt) {
                const int g = tok0 + 8 * tt + tg;
                float2 fi; fi.x = (float)i1; fi.y = (float)i2;
                ((float2*)out)[g] = fi;
                float2 fw; fw.x = w1; fw.y = w2;
                ((float2*)ow)[g] = fw;
            }
        }
    }
}

extern "C" void kernel_launch(void* const* d_in, const int* in_sizes, int n_in,
                              void* d_out, int out_size, void* d_ws, size_t ws_size,
                              hipStream_t stream) {
    const float* x = (const float*)d_in[0];
    const float* W = (const float*)d_in[1];
    const float* b = (const float*)d_in[2];
    float* out = (float*)d_out;
    float* Wq2 = (float*)d_ws;                       // 512 KB scratch
    const int n_tokens = in_sizes[0] / D_MODEL;      // 32768

    make_Wq2<<<(D_MODEL * N_EXP) / 256, 256, 0, stream>>>(W, Wq2);
    router_d<<<n_tokens / TOKS, 256, 0, stream>>>(x, (const float4*)Wq2, b, out, n_tokens);
}